// Round 4
// 3494.786 us; speedup vs baseline: 1.1921x; 1.1921x over previous
//
#include <hip/hip_runtime.h>

typedef _Float16 h2_t __attribute__((ext_vector_type(2)));

#define HID  100
#define TENC 4096
#define TDEC 4096
#define NCLS 6
#define NTHR 256   // 4 waves, one per SIMD

__device__ __forceinline__ float sigm(float v)  { return __builtin_amdgcn_rcpf(1.0f + __expf(-v)); }
__device__ __forceinline__ float tanh_(float v) { return 1.0f - 2.0f * __builtin_amdgcn_rcpf(1.0f + __expf(2.0f * v)); }

// lgkm-only barrier: does NOT drain vmcnt, so global stores stay in flight
// across steps (unlike __syncthreads).
#define SYNC_LDS() asm volatile("s_waitcnt lgkmcnt(0)\n\ts_barrier" ::: "memory")

__device__ __forceinline__ float packh2(float a, float b) {
    h2_t p; p[0] = (_Float16)a; p[1] = (_Float16)b;
    return __builtin_bit_cast(float, p);
}

// Pair sum with the adjacent lane (xor-1) on the VALU via DPP quad_perm
// [1,0,3,2] (0xB1) — the canonical rocPRIM butterfly step. Unlike the
// permlane32_swap attempts (R7-R9: three distinct failures from direction/
// coalescing/hazard ambiguity), quad_perm semantics are unambiguous and the
// BUILTIN lets the compiler insert any required hazard nops. Arithmetically
// identical to v + __shfl_xor(v,1): same two addends, commutative add.
__device__ __forceinline__ float xsum1(float v) {
    const int s = __builtin_amdgcn_update_dpp(
        0, __builtin_bit_cast(int, v), 0xB1, 0xF, 0xF, true);
    return v + __builtin_bit_cast(float, s);
}

// Persistent single-workgroup LSTM, v8. Diff vs v4 (R6, 4154-4166us, PASSED):
// the k-half partner moves from lane xor-32 to lane xor-1
// (cell = w*32 + (l>>1), khalf = l&1), so the k-reduction is a single-VALU
// DPP butterfly instead of 4 ds_bpermute round trips on the serial chain
// (DS ops/step/wave 13 -> 9). Weight fill, LDS layout, read/write patterns,
// activation formulas: byte-identical to v4 modulo the khalf re-key.
__global__ __launch_bounds__(NTHR, 1)
void lstm_rec(const float* __restrict__ x,      // [TENC*3]
              const int*   __restrict__ y,      // [TDEC]
              const float* __restrict__ eWih,   // [400*3]
              const float* __restrict__ eWhh,   // [400*HID]
              const float* __restrict__ ebih,
              const float* __restrict__ ebhh,
              const float* __restrict__ dWih,   // [400]
              const float* __restrict__ dWhh,
              const float* __restrict__ dbih,
              const float* __restrict__ dbhh,
              float* __restrict__ hsto)         // [(TDEC-1)*HID] decoder h history
{
    __shared__ __align__(16) _Float16 hbuf[2][2][64];  // [parity][k-half][50 used of 64]
    __shared__ __align__(8)  uint2    xst[TENC];       // packed f16: {x0,x1},{x2,1}
    __shared__               unsigned yst[TDEC];       // packed f16: {yf,0}

    const int  t     = threadIdx.x;
    const int  w     = t >> 6;
    const int  l     = t & 63;
    const int  khalf = l & 1;          // k-half on ADJACENT lanes (DPP-reachable)
    const int  cell  = w * 32 + (l >> 1);
    const bool live  = (cell < HID);
    const int  k0    = khalf * 50;

    // ---- stage x (f16 pairs) and y (f16) into LDS; zero h buffers ----
    for (int i = t; i < TENC; i += NTHR) {
        const float a = x[3*i], b = x[3*i+1], cc = x[3*i+2];
        uint2 u;
        u.x = __builtin_bit_cast(unsigned, packh2(a, b));
        u.y = __builtin_bit_cast(unsigned, packh2(cc, 1.0f));
        xst[i] = u;
    }
    for (int i = t; i < TDEC; i += NTHR)
        yst[i] = __builtin_bit_cast(unsigned, packh2((float)y[i], 0.0f));
    if (t < 256) ((_Float16*)hbuf)[t] = (_Float16)0.0f;

    // ---- encoder weights: 4 gates x 25 f16-pairs (k-half) per lane ----
    float wf[4][25];
    float wxp[4][2], bs[4];
    float c = 0.0f;
    #pragma unroll
    for (int r = 0; r < 4; ++r) {
        #pragma unroll
        for (int j = 0; j < 25; ++j) wf[r][j] = 0.0f;
        wxp[r][0] = wxp[r][1] = 0.0f; bs[r] = 0.0f;
    }
    if (live) {
        #pragma unroll
        for (int r = 0; r < 4; ++r) {
            const int row = cell + r * HID;
            #pragma unroll
            for (int j = 0; j < 25; ++j)
                wf[r][j] = packh2(eWhh[row*HID + k0 + 2*j], eWhh[row*HID + k0 + 2*j + 1]);
            if (khalf == 0) {  // input/bias fed once per pair, pre-reduction
                wxp[r][0] = packh2(eWih[row*3+0], eWih[row*3+1]);
                wxp[r][1] = packh2(eWih[row*3+2], 0.0f);
                bs[r]     = ebih[row] + ebhh[row];
            }
        }
    }
    __syncthreads();   // once, covers staging

    // hoisted write slots (cell is fixed per lane)
    const int hh2  = (cell < 50) ? 0 : 1;
    const int hoff = cell - 50 * hh2;

    int p = 0;

    // ================ encoder: 4096 steps ================
    for (int s = 0; s < TENC; ++s) {
        const float4* h4 = (const float4*)&hbuf[p][khalf][0];
        float hp[25];
        #pragma unroll
        for (int j = 0; j < 6; ++j) {      // 6 x ds_read_b128 = 24 pairs
            const float4 v = h4[j];
            hp[4*j+0] = v.x; hp[4*j+1] = v.y; hp[4*j+2] = v.z; hp[4*j+3] = v.w;
        }
        hp[24] = ((const float*)h4)[24];   // 25th pair (b32)

        // branchless input/bias contribution (odd lanes: wxp=bs=0 -> exact 0)
        const uint2 xp = xst[s];           // b64 broadcast
        const h2_t x0 = __builtin_bit_cast(h2_t, xp.x);
        const h2_t x1 = __builtin_bit_cast(h2_t, xp.y);
        float a0 = __builtin_amdgcn_fdot2(__builtin_bit_cast(h2_t, wxp[0][0]), x0,
                   __builtin_amdgcn_fdot2(__builtin_bit_cast(h2_t, wxp[0][1]), x1, bs[0], false), false);
        float a1 = __builtin_amdgcn_fdot2(__builtin_bit_cast(h2_t, wxp[1][0]), x0,
                   __builtin_amdgcn_fdot2(__builtin_bit_cast(h2_t, wxp[1][1]), x1, bs[1], false), false);
        float a2 = __builtin_amdgcn_fdot2(__builtin_bit_cast(h2_t, wxp[2][0]), x0,
                   __builtin_amdgcn_fdot2(__builtin_bit_cast(h2_t, wxp[2][1]), x1, bs[2], false), false);
        float a3 = __builtin_amdgcn_fdot2(__builtin_bit_cast(h2_t, wxp[3][0]), x0,
                   __builtin_amdgcn_fdot2(__builtin_bit_cast(h2_t, wxp[3][1]), x1, bs[3], false), false);

        #pragma unroll
        for (int j = 0; j < 25; ++j) {
            const h2_t hh = __builtin_bit_cast(h2_t, hp[j]);
            a0 = __builtin_amdgcn_fdot2(__builtin_bit_cast(h2_t, wf[0][j]), hh, a0, false);
            a1 = __builtin_amdgcn_fdot2(__builtin_bit_cast(h2_t, wf[1][j]), hh, a1, false);
            a2 = __builtin_amdgcn_fdot2(__builtin_bit_cast(h2_t, wf[2][j]), hh, a2, false);
            a3 = __builtin_amdgcn_fdot2(__builtin_bit_cast(h2_t, wf[3][j]), hh, a3, false);
        }

        // k-reduction across the lane pair: pure-VALU DPP butterfly
        a0 = xsum1(a0);
        a1 = xsum1(a1);
        a2 = xsum1(a2);
        a3 = xsum1(a3);

        const float fi = sigm(a0), ff = sigm(a1), fg = tanh_(a2), fo = sigm(a3);
        c = ff * c + fi * fg;              // replicated in both pair lanes
        const float hn = fo * tanh_(c);
        if (khalf == 0 && live)
            hbuf[p ^ 1][hh2][hoff] = (_Float16)hn;
        SYNC_LDS();
        p ^= 1;
    }

    // ================ swap to decoder weights ================
    float wdp[4], bsd[4];
    #pragma unroll
    for (int r = 0; r < 4; ++r) { wdp[r] = 0.0f; bsd[r] = 0.0f; }
    if (live) {
        #pragma unroll
        for (int r = 0; r < 4; ++r) {
            const int row = cell + r * HID;
            #pragma unroll
            for (int j = 0; j < 25; ++j)
                wf[r][j] = packh2(dWhh[row*HID + k0 + 2*j], dWhh[row*HID + k0 + 2*j + 1]);
            if (khalf == 0) {
                wdp[r] = packh2(dWih[row], 0.0f);
                bsd[r] = dbih[row] + dbhh[row];
            }
        }
    }

    // ================ decoder: 4095 steps (ratio==1 -> teacher-forced) ================
    for (int s = 0; s < TDEC - 1; ++s) {
        const float4* h4 = (const float4*)&hbuf[p][khalf][0];
        float hp[25];
        #pragma unroll
        for (int j = 0; j < 6; ++j) {
            const float4 v = h4[j];
            hp[4*j+0] = v.x; hp[4*j+1] = v.y; hp[4*j+2] = v.z; hp[4*j+3] = v.w;
        }
        hp[24] = ((const float*)h4)[24];

        // branchless scalar-input contribution (odd lanes: wdp=bsd=0)
        const h2_t yp = __builtin_bit_cast(h2_t, yst[s]);   // {yf, 0}
        float a0 = __builtin_amdgcn_fdot2(__builtin_bit_cast(h2_t, wdp[0]), yp, bsd[0], false);
        float a1 = __builtin_amdgcn_fdot2(__builtin_bit_cast(h2_t, wdp[1]), yp, bsd[1], false);
        float a2 = __builtin_amdgcn_fdot2(__builtin_bit_cast(h2_t, wdp[2]), yp, bsd[2], false);
        float a3 = __builtin_amdgcn_fdot2(__builtin_bit_cast(h2_t, wdp[3]), yp, bsd[3], false);

        #pragma unroll
        for (int j = 0; j < 25; ++j) {
            const h2_t hh = __builtin_bit_cast(h2_t, hp[j]);
            a0 = __builtin_amdgcn_fdot2(__builtin_bit_cast(h2_t, wf[0][j]), hh, a0, false);
            a1 = __builtin_amdgcn_fdot2(__builtin_bit_cast(h2_t, wf[1][j]), hh, a1, false);
            a2 = __builtin_amdgcn_fdot2(__builtin_bit_cast(h2_t, wf[2][j]), hh, a2, false);
            a3 = __builtin_amdgcn_fdot2(__builtin_bit_cast(h2_t, wf[3][j]), hh, a3, false);
        }

        a0 = xsum1(a0);
        a1 = xsum1(a1);
        a2 = xsum1(a2);
        a3 = xsum1(a3);

        const float fi = sigm(a0), ff = sigm(a1), fg = tanh_(a2), fo = sigm(a3);
        c = ff * c + fi * fg;
        const float hn = fo * tanh_(c);
        if (live) {
            if (khalf == 0) {
                hbuf[p ^ 1][hh2][hoff] = (_Float16)hn;
            } else {
                hsto[s * HID + cell] = hn;     // global store, never fenced in-loop
            }
        }
        SYNC_LDS();
        p ^= 1;
    }
    // kernel end-of-dispatch drains the hsto stores before logits_k launches
}

// Parallel logits: out[t][r] = linW[r] . h_t + linb[r], last row zeroed.
__global__ __launch_bounds__(256)
void logits_k(const float* __restrict__ hsto, const float* __restrict__ linW,
              const float* __restrict__ linb, float* __restrict__ out)
{
    const int idx = blockIdx.x * 256 + threadIdx.x;
    if (idx >= TDEC * NCLS) return;
    const int tt = idx / NCLS;
    const int r  = idx % NCLS;
    if (tt >= TDEC - 1) { out[idx] = 0.0f; return; }
    const float* h  = hsto + tt * HID;
    const float* wr = linW + r * HID;
    float a = linb[r];
    #pragma unroll 4
    for (int k = 0; k < HID; ++k) a += wr[k] * h[k];
    out[idx] = a;
}

extern "C" void kernel_launch(void* const* d_in, const int* in_sizes, int n_in,
                              void* d_out, int out_size, void* d_ws, size_t ws_size,
                              hipStream_t stream)
{
    const float* x    = (const float*)d_in[0];
    const int*   y    = (const int*)  d_in[1];
    const float* eWih = (const float*)d_in[2];
    const float* eWhh = (const float*)d_in[3];
    const float* ebih = (const float*)d_in[4];
    const float* ebhh = (const float*)d_in[5];
    const float* dWih = (const float*)d_in[6];
    const float* dWhh = (const float*)d_in[7];
    const float* dbih = (const float*)d_in[8];
    const float* dbhh = (const float*)d_in[9];
    const float* linW = (const float*)d_in[10];
    const float* linb = (const float*)d_in[11];
    float* out  = (float*)d_out;
    float* hsto = (float*)d_ws;   // (TDEC-1)*HID*4 = 1.64 MB scratch

    lstm_rec<<<dim3(1), dim3(NTHR), 0, stream>>>(
        x, y, eWih, eWhh, ebih, ebhh, dWih, dWhh, dbih, dbhh, hsto);

    const int nout = TDEC * NCLS;
    logits_k<<<dim3((nout + 255) / 256), dim3(256), 0, stream>>>(hsto, linW, linb, out);
}